// Round 7
// baseline (66.320 us; speedup 1.0000x reference)
//
#include <hip/hip_runtime.h>
#include <hip/hip_fp16.h>

#define K_EPSILON 0.0001f

constexpr int N = 4, K = 8, H = 256, W = 256, C = 64;

// ---------------------------------------------------------------------------
// Pre-pass: quantize ptclds (C=64,P) fp32 -> 2-slice int8 table + f32 scale.
//   table[(s*P + p)*32 + i] = round(v[c=32s+i]/scale_p) + 128  (biased u8)
//   scale[p] = max_c |v| / 127
// One slice = P*32B = 3.2MB -> resident in one XCD's 4MiB L2.
// ---------------------------------------------------------------------------
__global__ __launch_bounds__(256) void quantize_pt(
    const float* __restrict__ src, uint8_t* __restrict__ table,
    float* __restrict__ scale, int P) {
  __shared__ float tile[64][129];  // 33KB
  __shared__ float s_inv[128];
  const int t = threadIdx.x;
  const int p0 = blockIdx.x * 128;
  const int pl = t & 127, ch2 = t >> 7;

  #pragma unroll
  for (int i = 0; i < 32; ++i) {
    int c = i * 2 + ch2;
    int p = p0 + pl;
    tile[c][pl] = (p < P) ? src[(size_t)c * P + p] : 0.0f;
  }
  __syncthreads();

  if (t < 128) {
    float m = 1e-9f;
    #pragma unroll
    for (int c = 0; c < 64; ++c) m = fmaxf(m, fabsf(tile[c][t]));
    int p = p0 + t;
    if (p < P) scale[p] = m / 127.0f;
    s_inv[t] = 127.0f / m;
  }
  __syncthreads();

  const int pw = t >> 1, jc = t & 1;
  const int p = p0 + pw;
  if (p < P) {
    float inv = s_inv[pw];
    #pragma unroll
    for (int s = 0; s < 2; ++s) {
      uint32_t wv[4];
      #pragma unroll
      for (int q = 0; q < 4; ++q) {
        uint32_t b = 0;
        #pragma unroll
        for (int b4 = 0; b4 < 4; ++b4) {
          int c = s * 32 + jc * 16 + q * 4 + b4;
          int u = (int)rintf(tile[c][pw] * inv) + 128;
          b |= ((uint32_t)(u & 255)) << (8 * b4);
        }
        wv[q] = b;
      }
      *(uint4*)&table[((size_t)s * P + p) * 32 + jc * 16] =
          make_uint4(wv[0], wv[1], wv[2], wv[3]);
    }
  }
}

// ---------------------------------------------------------------------------
// Main: one block = 128 pixels (half (n,h) row) x one 32-channel slice.
// slice = (B&7)>>2: slice s lives on XCDs {4s..4s+3} (round-robin %8) so its
// 3.2MB table stays L2-resident -> gathers are L2 hits (R3 proved residency).
// Phase 1 (pack): thread t = pixel t; gathers scale[idx], folds mask,
//   1/max(den,eps) and scale into ws_k; bias = 128*sum(ws) for biased-u8.
// Phase 2: wave = 32 pixels x 2 lanes; lane loads uint4 = 16 int8 channels
//   -> 1KB/wave-instr, 8 independent K-gathers, cvt_f32_ubyte + fmac decode.
// Phase 3: coalesced channel-plane stores via fp32 LDS tile.
// ---------------------------------------------------------------------------
__global__ __launch_bounds__(256) void compositor_resident(
    const int* __restrict__ frag, const float* __restrict__ alpha,
    const uint8_t* __restrict__ table, const float* __restrict__ scale,
    float* __restrict__ out, int P) {
  __shared__ uint32_t s_idx[128][9];   // 4.6KB, stride 9 (odd)
  __shared__ float    s_ws[128][11];   // 5.6KB, [0..7]=ws, [8]=bias, stride 11
  __shared__ float    s_out[128][33];  // 16.9KB
  const int t = threadIdx.x;
  const int B = blockIdx.x;                    // 0..4095
  const int slice = (B & 7) >> 2;              // XCD affinity
  const int rid = ((B >> 3) << 2) | (B & 3);   // 0..2047, bijective
  const int row = rid >> 1;                    // 0..1023
  const int n = row >> 8, h = row & 255;
  const int w0 = (rid & 1) * 128;

  // ---- Phase 1: pack ----
  if (t < 128) {
    float a[K];
    int id[K];
    float den = 0.0f;
    #pragma unroll
    for (int k = 0; k < K; ++k) {
      size_t g = (((size_t)(n * K + k)) << 16) + ((size_t)h << 8) + w0 + t;
      int idx = frag[g];
      float av = alpha[g];
      bool m = idx >= 0;
      id[k] = m ? idx : 0;
      a[k] = m ? av : 0.0f;
      den += a[k];
    }
    float inv = 1.0f / fmaxf(den, K_EPSILON);
    float bias = 0.0f;
    #pragma unroll
    for (int k = 0; k < K; ++k) {
      float ws = a[k] * inv * scale[id[k]];  // scale: 400KB, L2-resident
      s_ws[t][k] = ws;
      s_idx[t][k] = (uint32_t)id[k];
      bias += ws;
    }
    s_ws[t][8] = 128.0f * bias;
  }
  __syncthreads();

  // ---- Phase 2: resident int8 gather ----
  const uint8_t* tab = table + (size_t)slice * P * 32;
  const int lane = t & 63, wid = t >> 6;
  const int pg = lane >> 1, jc = lane & 1;  // 32 pixels x 2 chunks per wave
  const int pix = wid * 32 + pg;

  float acc[16];
  {
    float bias = s_ws[pix][8];
    #pragma unroll
    for (int i = 0; i < 16; ++i) acc[i] = -bias;
  }
  #pragma unroll
  for (int k = 0; k < K; ++k) {
    uint32_t idx = s_idx[pix][k];
    float ws = s_ws[pix][k];
    uint4 d = *(const uint4*)(tab + ((size_t)idx << 5) + (jc << 4));
    uint32_t wd[4] = {d.x, d.y, d.z, d.w};
    #pragma unroll
    for (int q = 0; q < 4; ++q) {
      #pragma unroll
      for (int b = 0; b < 4; ++b) {
        acc[q * 4 + b] += ws * (float)((wd[q] >> (8 * b)) & 255u);
      }
    }
  }
  {
    float* row_out = &s_out[pix][jc * 16];
    #pragma unroll
    for (int i = 0; i < 16; ++i) row_out[i] = acc[i];
  }
  __syncthreads();

  // ---- Phase 3: coalesced output (this slice's 32 c-planes) ----
  const int w = t & 127, half = t >> 7;
  const size_t base = ((size_t)h << 8) + w0 + w;
  #pragma unroll
  for (int ii = 0; ii < 16; ++ii) {
    int i = half * 16 + ii;
    int c = slice * 32 + i;
    out[(((size_t)(n * C + c)) << 16) + base] = s_out[w][i];
  }
}

// ---------------------------------------------------------------------------
// Fallback (workspace too small): fp32 strided gather, known-correct from R1.
// ---------------------------------------------------------------------------
__global__ __launch_bounds__(256) void compositor_fallback(
    const int* __restrict__ frag, const float* __restrict__ alpha,
    const float* __restrict__ pt, float* __restrict__ out, int P) {
  __shared__ int   s_idx[K][64];
  __shared__ float s_a[K][64];
  __shared__ float s_out[64][67];

  const int t = threadIdx.x;
  const int tile = blockIdx.x;
  const int w0 = (tile & 3) * 64;
  const int h = (tile >> 2) & (H - 1);
  const int n = tile >> 10;

  #pragma unroll
  for (int i = 0; i < 2; ++i) {
    int f = t + i * 256;
    int k = f >> 6, wo = f & 63;
    size_t g = (((size_t)(n * K + k) * H + h) * W) + w0 + wo;
    s_idx[k][wo] = frag[g];
    s_a[k][wo]   = alpha[g];
  }
  __syncthreads();

  const int lane = t & 63;
  const int wid  = t >> 6;
  for (int jj = 0; jj < 16; ++jj) {
    int pix = wid * 16 + jj;
    float acc = 0.0f, den = 0.0f;
    #pragma unroll
    for (int k = 0; k < K; ++k) {
      int idx = s_idx[k][pix];
      float a = s_a[k][pix];
      if (idx < 0) a = 0.0f;
      int safe = idx < 0 ? 0 : idx;
      acc += a * pt[(size_t)lane * P + safe];
      den += a;
    }
    s_out[pix][lane] = acc / fmaxf(den, K_EPSILON);
  }
  __syncthreads();

  #pragma unroll
  for (int i = 0; i < 16; ++i) {
    int c = (t >> 6) + i * 4;
    int wo = t & 63;
    size_t g = (((size_t)(n * C + c) * H + h) * W) + w0 + wo;
    out[g] = s_out[wo][c];
  }
}

extern "C" void kernel_launch(void* const* d_in, const int* in_sizes, int n_in,
                              void* d_out, int out_size, void* d_ws, size_t ws_size,
                              hipStream_t stream) {
  const int*   frag   = (const int*)d_in[0];
  const float* alpha  = (const float*)d_in[1];
  const float* ptclds = (const float*)d_in[2];
  float*       out    = (float*)d_out;

  const int P = in_sizes[2] / C;  // 100000
  const size_t tableBytes = (size_t)P * C;            // 6.4 MB (int8, 2 slices)
  const size_t scaleBytes = (size_t)P * sizeof(float);  // 400 KB

  if (ws_size >= tableBytes + scaleBytes) {
    uint8_t* tab = (uint8_t*)d_ws;
    float*   sc  = (float*)((char*)d_ws + tableBytes);
    quantize_pt<<<(P + 127) / 128, 256, 0, stream>>>(ptclds, tab, sc, P);
    compositor_resident<<<2 * 2 * N * H, 256, 0, stream>>>(frag, alpha, tab,
                                                           sc, out, P);
  } else {
    compositor_fallback<<<N * H * (W / 64), 256, 0, stream>>>(frag, alpha,
                                                              ptclds, out, P);
  }
}

// Round 8
// 59.067 us; speedup vs baseline: 1.1228x; 1.1228x over previous
//
#include <hip/hip_runtime.h>
#include <hip/hip_fp16.h>

#define K_EPSILON 0.0001f

constexpr int N = 4, K = 8, H = 256, W = 256, C = 64;

// ---------------------------------------------------------------------------
// Pre-pass: quantize ptclds (C=64,P) fp32 -> (P,64) biased-u8 + f32 scale[P].
//   table[p*64 + c] = round(v/scale_p) + 128;  scale_p = max_c|v| / 127
// Table = 6.4MB. One pixel-column = 64B = one full cache line.
// ---------------------------------------------------------------------------
__global__ __launch_bounds__(256) void quantize_pt(
    const float* __restrict__ src, uint8_t* __restrict__ table,
    float* __restrict__ scale, int P) {
  __shared__ float tile[64][129];
  __shared__ float s_inv[128];
  const int t = threadIdx.x;
  const int p0 = blockIdx.x * 128;
  const int pl = t & 127, ch2 = t >> 7;

  #pragma unroll
  for (int i = 0; i < 32; ++i) {
    int c = i * 2 + ch2;
    int p = p0 + pl;
    tile[c][pl] = (p < P) ? src[(size_t)c * P + p] : 0.0f;
  }
  __syncthreads();

  if (t < 128) {
    float m = 1e-9f;
    #pragma unroll
    for (int c = 0; c < 64; ++c) m = fmaxf(m, fabsf(tile[c][t]));
    int p = p0 + t;
    if (p < P) scale[p] = m / 127.0f;
    s_inv[t] = 127.0f / m;
  }
  __syncthreads();

  const int pw = t >> 1, jc = t & 1;  // thread covers 32 bytes of one point
  const int p = p0 + pw;
  if (p < P) {
    float inv = s_inv[pw];
    uint32_t wv[8];
    #pragma unroll
    for (int q = 0; q < 8; ++q) {
      uint32_t b = 0;
      #pragma unroll
      for (int b4 = 0; b4 < 4; ++b4) {
        int c = jc * 32 + q * 4 + b4;
        int u = (int)rintf(tile[c][pw] * inv) + 128;
        b |= ((uint32_t)(u & 255)) << (8 * b4);
      }
      wv[q] = b;
    }
    uint8_t* dstp = &table[(size_t)p * 64 + jc * 32];
    *(uint4*)dstp        = make_uint4(wv[0], wv[1], wv[2], wv[3]);
    *(uint4*)(dstp + 16) = make_uint4(wv[4], wv[5], wv[6], wv[7]);
  }
}

// ---------------------------------------------------------------------------
// Fused main (R6 structure, int8 table): block = 128 pixels, 256 threads.
// Phase 1 (pack, threads 0..127): ws_k = alpha_k/max(den,eps)*scale[idx_k];
//   LDS row per pixel: [0..7]=idx, [8..15]=ws bits, [16]=128*sum(ws).
// Phase 2: wave = 8 pixels x 8 lanes; lane jc loads uint2 = 8B = channels
//   [8jc,8jc+8) -> 64B/pixel full-line gathers, 512B/wave-instr, 8 K-gathers
//   fully unrolled. Decode = v_cvt_f32_ubyte + fmac, bias folded into init.
// Phase 3: half2 staging (16.9KB) -> coalesced channel-plane stores.
// ---------------------------------------------------------------------------
__global__ __launch_bounds__(256, 6) void compositor_u8(
    const int* __restrict__ frag, const float* __restrict__ alpha,
    const uint8_t* __restrict__ table, const float* __restrict__ scale,
    float* __restrict__ out, int P) {
  __shared__ uint32_t s_pk[128][17];   // 8.7KB, odd stride
  __shared__ __half2  s_out[128][33];  // 16.9KB, odd stride
  const int t = threadIdx.x;
  const int B = blockIdx.x;           // 0..2047
  const int rowid = B >> 1;
  const int n = rowid >> 8, h = rowid & 255;
  const int w0 = (B & 1) * 128;

  // ---- Phase 1: pack ----
  if (t < 128) {
    float a[K];
    int id[K];
    float den = 0.0f;
    #pragma unroll
    for (int k = 0; k < K; ++k) {
      size_t g = (((size_t)(n * K + k)) << 16) + ((size_t)h << 8) + w0 + t;
      int idx = frag[g];
      float av = alpha[g];
      bool m = idx >= 0;
      id[k] = m ? idx : 0;
      a[k] = m ? av : 0.0f;
      den += a[k];
    }
    float inv = 1.0f / fmaxf(den, K_EPSILON);
    float bias = 0.0f;
    #pragma unroll
    for (int k = 0; k < K; ++k) {
      float ws = a[k] * inv * scale[id[k]];  // scale[]: 400KB, L2-resident
      s_pk[t][k] = (uint32_t)id[k];
      s_pk[t][8 + k] = __float_as_uint(ws);
      bias += ws;
    }
    s_pk[t][16] = __float_as_uint(128.0f * bias);
  }
  __syncthreads();

  // ---- Phase 2: int8 wide gather ----
  const int lane = t & 63, wid = t >> 6;
  const int pg = lane >> 3;   // pixel within wave-group (8 px/wave)
  const int jc = lane & 7;    // 8B chunk = channels [8jc, 8jc+8)

  #pragma unroll
  for (int iter = 0; iter < 4; ++iter) {
    int pix = iter * 32 + wid * 8 + pg;
    float acc0, acc1, acc2, acc3, acc4, acc5, acc6, acc7;
    {
      float nb = -__uint_as_float(s_pk[pix][16]);
      acc0 = acc1 = acc2 = acc3 = acc4 = acc5 = acc6 = acc7 = nb;
    }
    #pragma unroll
    for (int k = 0; k < K; ++k) {
      uint32_t idx = s_pk[pix][k];           // 8-lane broadcast
      float ws = __uint_as_float(s_pk[pix][8 + k]);
      uint2 d = *(const uint2*)(table + ((size_t)idx << 6) + (jc << 3));
      acc0 += ws * (float)(d.x & 255u);
      acc1 += ws * (float)((d.x >> 8) & 255u);
      acc2 += ws * (float)((d.x >> 16) & 255u);
      acc3 += ws * (float)(d.x >> 24);
      acc4 += ws * (float)(d.y & 255u);
      acc5 += ws * (float)((d.y >> 8) & 255u);
      acc6 += ws * (float)((d.y >> 16) & 255u);
      acc7 += ws * (float)(d.y >> 24);
    }
    __half2* row = &s_out[pix][4 * jc];
    row[0] = __floats2half2_rn(acc0, acc1);
    row[1] = __floats2half2_rn(acc2, acc3);
    row[2] = __floats2half2_rn(acc4, acc5);
    row[3] = __floats2half2_rn(acc6, acc7);
  }
  __syncthreads();

  // ---- Phase 3: coalesced output ----
  const int w = t & 127, hh = t >> 7;
  const size_t base = ((size_t)h << 8) + w0 + w;
  #pragma unroll
  for (int ii = 0; ii < 16; ++ii) {
    int i = hh * 16 + ii;  // half2 slot -> channels 2i, 2i+1
    float2 f = __half22float2(s_out[w][i]);
    out[(((size_t)(n * C + 2 * i)) << 16) + base]     = f.x;
    out[(((size_t)(n * C + 2 * i + 1)) << 16) + base] = f.y;
  }
}

// ---------------------------------------------------------------------------
// Fallback (workspace too small): fp32 strided gather, known-correct from R1.
// ---------------------------------------------------------------------------
__global__ __launch_bounds__(256) void compositor_fallback(
    const int* __restrict__ frag, const float* __restrict__ alpha,
    const float* __restrict__ pt, float* __restrict__ out, int P) {
  __shared__ int   s_idx[K][64];
  __shared__ float s_a[K][64];
  __shared__ float s_out[64][67];

  const int t = threadIdx.x;
  const int tile = blockIdx.x;
  const int w0 = (tile & 3) * 64;
  const int h = (tile >> 2) & (H - 1);
  const int n = tile >> 10;

  #pragma unroll
  for (int i = 0; i < 2; ++i) {
    int f = t + i * 256;
    int k = f >> 6, wo = f & 63;
    size_t g = (((size_t)(n * K + k) * H + h) * W) + w0 + wo;
    s_idx[k][wo] = frag[g];
    s_a[k][wo]   = alpha[g];
  }
  __syncthreads();

  const int lane = t & 63;
  const int wid  = t >> 6;
  for (int jj = 0; jj < 16; ++jj) {
    int pix = wid * 16 + jj;
    float acc = 0.0f, den = 0.0f;
    #pragma unroll
    for (int k = 0; k < K; ++k) {
      int idx = s_idx[k][pix];
      float a = s_a[k][pix];
      if (idx < 0) a = 0.0f;
      int safe = idx < 0 ? 0 : idx;
      acc += a * pt[(size_t)lane * P + safe];
      den += a;
    }
    s_out[pix][lane] = acc / fmaxf(den, K_EPSILON);
  }
  __syncthreads();

  #pragma unroll
  for (int i = 0; i < 16; ++i) {
    int c = (t >> 6) + i * 4;
    int wo = t & 63;
    size_t g = (((size_t)(n * C + c) * H + h) * W) + w0 + wo;
    out[g] = s_out[wo][c];
  }
}

extern "C" void kernel_launch(void* const* d_in, const int* in_sizes, int n_in,
                              void* d_out, int out_size, void* d_ws, size_t ws_size,
                              hipStream_t stream) {
  const int*   frag   = (const int*)d_in[0];
  const float* alpha  = (const float*)d_in[1];
  const float* ptclds = (const float*)d_in[2];
  float*       out    = (float*)d_out;

  const int P = in_sizes[2] / C;  // 100000
  const size_t tableBytes = (size_t)P * C;              // 6.4 MB int8
  const size_t scaleBytes = (size_t)P * sizeof(float);  // 400 KB

  if (ws_size >= tableBytes + scaleBytes) {
    uint8_t* tab = (uint8_t*)d_ws;
    float*   sc  = (float*)((char*)d_ws + tableBytes);
    quantize_pt<<<(P + 127) / 128, 256, 0, stream>>>(ptclds, tab, sc, P);
    compositor_u8<<<2 * N * H, 256, 0, stream>>>(frag, alpha, tab, sc, out, P);
  } else {
    compositor_fallback<<<N * H * (W / 64), 256, 0, stream>>>(frag, alpha,
                                                              ptclds, out, P);
  }
}